// Round 5
// baseline (227.556 us; speedup 1.0000x reference)
//
#include <hip/hip_runtime.h>

// ---------------------------------------------------------------------------
// out[n] = x_n^T A x_n / (x_n^T x_n),  A = Re(U^H Z U), U = full circuit unitary
// Kernel 1: simulate circuit on 128 basis columns -> U (complex fp32) in ws
// Kernel 2: A_ij = sum_k z_k (Ur_ki Ur_kj + Ui_ki Ui_kj) -> bf16 A in ws
// Kernel 3: bf16 MFMA GEMM y = A x fused with dot/norm epilogue, LDS-free
//
// R10 -> R11: R10 (prefetch lo-half only) stayed ~60-70 us vs 21 us HBM
// roofline. Diagnosis: hi/xe consumption relied on L1/L2 hits, but the live
// window (8 waves/CU x 24 KB = 192 KB) exceeds L1 (32 KB) and the per-CU L2
// share (~128 KB); aggregate in-flight > 4 MB/XCD -> hi/xe re-fetch from HBM
// (traffic amplification) AND expose full memory latency on the pack->MFMA
// path every iteration. R11: prefetch BOTH halves (lo+hi, 32 VGPRs) of the
// next tile into REGISTERS one iteration ahead -> B-path never touches cache;
// only the epilogue xe loads are cache-dependent, and their window (current
// tile only, 8 waves x 8 KB = 64 KB/CU) fits the L2 share comfortably.
// X is read from HBM exactly once. VGPR ~250 < 256 -> 2 waves/SIMD holds.
// Numerics: identical values + op order to R10 -> absmax 0.001953125.
// Predicted: vqa_main ~25-35 us (>=4 TB/s), dur_us 216 -> ~180-190.
// If dur_us moves <10 us: kernels already small, floor is harness-fixed ->
// ROOFLINE next round.
// ---------------------------------------------------------------------------

#define N_QUBITS 7
#define DIM 128
#define N_LAYERS 4
#define BATCH 262144
#define GRID 1024
#define ROWS 32                          // rows per tile (16 per wave)
#define ITERS (BATCH / (GRID * ROWS))    // 8

typedef short short8 __attribute__((ext_vector_type(8)));
typedef float f32x4 __attribute__((ext_vector_type(4)));

__device__ __forceinline__ unsigned short f2bf(float f) {
  unsigned u = __builtin_bit_cast(unsigned, f);
  u += 0x7fffu + ((u >> 16) & 1u);   // RNE
  return (unsigned short)(u >> 16);
}

// [bf16(x) | bf16(y)<<16]: round-half-up add + v_perm byte select
__device__ __forceinline__ unsigned pk2(float x, float y) {
  unsigned ux = __builtin_bit_cast(unsigned, x) + 0x8000u;
  unsigned uy = __builtin_bit_cast(unsigned, y) + 0x8000u;
  return __builtin_amdgcn_perm(uy, ux, 0x07060302u);
}

__device__ __forceinline__ short8 pack_bf16(float4 lo, float4 hi) {
  uint4 d;
  d.x = pk2(lo.x, lo.y);
  d.y = pk2(lo.z, lo.w);
  d.z = pk2(hi.x, hi.y);
  d.w = pk2(hi.z, hi.w);
  return __builtin_bit_cast(short8, d);
}

// ---------------------------------------------------------------------------
// Kernel 1: one block (64 threads) per column c. State (128 complex) in LDS.
// Qubit w <-> bit (6-w) of the flattened index.  (unchanged, verified)
// ---------------------------------------------------------------------------
__global__ void sim_columns(const float* __restrict__ W,
                            float* __restrict__ Ur, float* __restrict__ Ui) {
  __shared__ float sr[DIM], si[DIM];
  const int c = blockIdx.x;
  const int t = threadIdx.x;  // 0..63

  sr[t] = (t == c) ? 1.f : 0.f;        si[t] = 0.f;
  sr[t + 64] = (t + 64 == c) ? 1.f : 0.f;  si[t + 64] = 0.f;
  __syncthreads();

  for (int l = 0; l < N_LAYERS; ++l) {
    for (int w = 0; w < N_QUBITS; ++w) {
      const float phi = W[(l * 7 + w) * 3 + 0];
      const float th  = W[(l * 7 + w) * 3 + 1];
      const float om  = W[(l * 7 + w) * 3 + 2];
      const float ch = __cosf(0.5f * th), sh = __sinf(0.5f * th);
      const float ap = 0.5f * (phi + om), am = 0.5f * (phi - om);
      const float cap = __cosf(ap), sap = __sinf(ap);
      const float cam = __cosf(am), sam = __sinf(am);
      const float ar =  cap * ch, ai = -sap * ch;
      const float br = -cam * sh, bi = -sam * sh;
      const float cr =  cam * sh, ci = -sam * sh;
      const float dr =  cap * ch, di =  sap * ch;

      const int m = 1 << (6 - w);
      const int i0 = ((t & ~(m - 1)) << 1) | (t & (m - 1));
      const int i1 = i0 | m;
      const float x0r = sr[i0], x0i = si[i0];
      const float x1r = sr[i1], x1i = si[i1];
      __syncthreads();
      sr[i0] = ar * x0r - ai * x0i + br * x1r - bi * x1i;
      si[i0] = ar * x0i + ai * x0r + br * x1i + bi * x1r;
      sr[i1] = cr * x0r - ci * x0i + dr * x1r - di * x1i;
      si[i1] = cr * x0i + ci * x0r + dr * x1i + di * x1r;
      __syncthreads();
    }
    const int r = (l % (N_QUBITS - 1)) + 1;  // ranges [1,2,3,4]
    for (int w = 0; w < N_QUBITS; ++w) {
      const int ctrl = w, tgt = (w + r) % N_QUBITS;
      const int cmask = 1 << (6 - ctrl), tmask = 1 << (6 - tgt);
      const int i0 = ((t & ~(tmask - 1)) << 1) | (t & (tmask - 1));
      const int i1 = i0 | tmask;
      const float a0r = sr[i0], a0i = si[i0];
      const float a1r = sr[i1], a1i = si[i1];
      __syncthreads();
      if (i0 & cmask) {
        sr[i0] = a1r; si[i0] = a1i;
        sr[i1] = a0r; si[i1] = a0i;
      }
      __syncthreads();
    }
  }
  Ur[(size_t)t * DIM + c]        = sr[t];
  Ui[(size_t)t * DIM + c]        = si[t];
  Ur[(size_t)(t + 64) * DIM + c] = sr[t + 64];
  Ui[(size_t)(t + 64) * DIM + c] = si[t + 64];
}

// ---------------------------------------------------------------------------
// Kernel 2: A_ij, identity k-layout. 128 blocks (row i) x 128 threads (j).
// Ur[k][i] broadcasts; Ur[k][j] coalesces; all L2-hot.  (unchanged, verified)
// ---------------------------------------------------------------------------
__global__ void build_A(const float* __restrict__ Ur, const float* __restrict__ Ui,
                        unsigned short* __restrict__ Ab) {
  const int i = blockIdx.x;
  const int j = threadIdx.x;
  float s = 0.f;
#pragma unroll 8
  for (int k = 0; k < DIM; ++k) {
    const float zk = (((k >> 6) ^ k) & 1) ? -1.f : 1.f;
    s += zk * (Ur[k * DIM + i] * Ur[k * DIM + j] + Ui[k * DIM + i] * Ui[k * DIM + j]);
  }
  Ab[i * DIM + j] = f2bf(s);
}

// ---------------------------------------------------------------------------
// Kernel 3. LDS-free, full-register B pipeline. Block = 2 waves; wave w owns
// tile rows 16w..16w+15.
//   A-frag: a_frag[kt][t] = Ab[16t + n16][32kt + 8g .. +8]   (128 VGPRs)
//   B-data: lane (n16,g) holds x[R][32kt+8g .. +8] as lo/hi float4 pairs
//           (64 VGPRs: current + next tile), prefetched one iter ahead.
//   C/D:    acc[t][r] = y[16t + 4g + r][row R]; epilogue xe = chunk (4t+g),
//           read from global -- L2-hit (lines fetched by the reg loads one
//           full iteration earlier; window 8 waves x 8 KB = 64 KB/CU).
// ---------------------------------------------------------------------------
__global__ __launch_bounds__(128, 2) void vqa_main(const float* __restrict__ X,
                                                   const unsigned short* __restrict__ Ab,
                                                   float* __restrict__ out) {
  const int tid = threadIdx.x;   // 0..127
  const int lane = tid & 63;
  const int wave = tid >> 6;     // 0..1
  const int n16 = lane & 15;
  const int g = lane >> 4;
  const int R = 16 * wave + n16; // this lane's row within the tile (0..31)

  // this lane's row pointer within tile 0, and per-iteration stride
  const size_t step = (size_t)GRID * ROWS * DIM;
  const float* p = X + (size_t)blockIdx.x * (ROWS * DIM) + R * DIM;

  // prologue: tile 0's FULL data (lo+hi) into registers
  float4 lo[4], hi[4];
#pragma unroll
  for (int kt = 0; kt < 4; ++kt) {
    lo[kt] = *reinterpret_cast<const float4*>(p + 32 * kt + 8 * g);
    hi[kt] = *reinterpret_cast<const float4*>(p + 32 * kt + 8 * g + 4);
  }

  // loop-invariant A fragments -> registers (32 x 16 B = 128 VGPRs); L2-hot
  short8 a_frag[4][8];
#pragma unroll
  for (int kt = 0; kt < 4; ++kt)
#pragma unroll
    for (int t = 0; t < 8; ++t)
      a_frag[kt][t] = *reinterpret_cast<const short8*>(
          Ab + (16 * t + n16) * DIM + 32 * kt + 8 * g);

#pragma unroll 1
  for (int it = 0; it < ITERS; ++it) {
    // prefetch next tile's FULL data into registers (no cache reliance)
    float4 nlo[4], nhi[4];
    const bool more = (it + 1 < ITERS);
    if (more) {
#pragma unroll
      for (int kt = 0; kt < 4; ++kt) {
        nlo[kt] = *reinterpret_cast<const float4*>(p + step + 32 * kt + 8 * g);
        nhi[kt] = *reinterpret_cast<const float4*>(p + step + 32 * kt + 8 * g + 4);
      }
    }

    short8 bfrag[4];
#pragma unroll
    for (int kt = 0; kt < 4; ++kt)
      bfrag[kt] = pack_bf16(lo[kt], hi[kt]);

    f32x4 acc[8];
#pragma unroll
    for (int t = 0; t < 8; ++t) acc[t] = (f32x4){0.f, 0.f, 0.f, 0.f};
#pragma unroll
    for (int kt = 0; kt < 4; ++kt) {
#pragma unroll
      for (int t = 0; t < 8; ++t)
        acc[t] = __builtin_amdgcn_mfma_f32_16x16x32_bf16(a_frag[kt][t], bfrag[kt],
                                                         acc[t], 0, 0, 0);
    }

    // epilogue: xe chunks (4t+g) from global -- L2-hit (current tile's lines
    // were fetched by the reg loads one iteration ago)
    float dot = 0.f, nrm = 0.f;
#pragma unroll
    for (int t = 0; t < 8; ++t) {
      const float4 xe = *reinterpret_cast<const float4*>(p + 16 * t + 4 * g);
      dot += xe.x * acc[t][0] + xe.y * acc[t][1] + xe.z * acc[t][2] + xe.w * acc[t][3];
      nrm += xe.x * xe.x + xe.y * xe.y + xe.z * xe.z + xe.w * xe.w;
    }
    dot += __shfl_xor(dot, 16, 64);
    dot += __shfl_xor(dot, 32, 64);
    nrm += __shfl_xor(nrm, 16, 64);
    nrm += __shfl_xor(nrm, 32, 64);
    if (g == 0) out[(blockIdx.x + it * GRID) * ROWS + R] = dot / nrm;

    if (more) {
#pragma unroll
      for (int kt = 0; kt < 4; ++kt) { lo[kt] = nlo[kt]; hi[kt] = nhi[kt]; }
    }
    p += step;
  }
}

// ---------------------------------------------------------------------------
extern "C" void kernel_launch(void* const* d_in, const int* in_sizes, int n_in,
                              void* d_out, int out_size, void* d_ws, size_t ws_size,
                              hipStream_t stream) {
  const float* X = (const float*)d_in[0];   // (262144, 128) fp32
  const float* W = (const float*)d_in[1];   // (4, 7, 3) fp32
  float* out = (float*)d_out;               // (262144,) fp32

  float* Ur = (float*)d_ws;
  float* Ui = Ur + DIM * DIM;
  unsigned short* Ab = (unsigned short*)(Ui + DIM * DIM);

  sim_columns<<<DIM, 64, 0, stream>>>(W, Ur, Ui);
  build_A<<<DIM, DIM, 0, stream>>>(Ur, Ui, Ab);
  vqa_main<<<GRID, 128, 0, stream>>>(X, Ab, out);
}

// Round 6
// 212.033 us; speedup vs baseline: 1.0732x; 1.0732x over previous
//
#include <hip/hip_runtime.h>

// ---------------------------------------------------------------------------
// out[n] = x_n^T A x_n / (x_n^T x_n),  A = Re(U^H Z U), U = full circuit unitary
// Kernel 1: simulate circuit on 128 basis columns -> U (complex fp32) in ws
// Kernel 2: A_ij = sum_k z_k (Ur_ki Ur_kj + Ui_ki Ui_kj) -> bf16 A in ws
// Kernel 3: bf16 MFMA GEMM y = A x fused with dot/norm epilogue
//
// R11 -> R12: decomposition vs the R9 anchor (fused kernel 200.5 us, bench
// 331 -> fixed overhead ~131 us): controllable kernel time R7 ~77 us,
// R10 ~85, R11 ~96. The LDS-free experiments REGRESSED (VGPR pressure at the
// 256 cap + epilogue xe re-reads costing HBM instead of LDS). Revert to the
// best-measured structure (R7: global_load_lds staging, counted vmcnt,
// A-in-registers, LDS epilogue re-read) and pull the one untested lever:
// OCCUPANCY. DEPTH 4->2 halves LDS to 32 KB -> 4 blocks/CU resident at
// GRID 1024 (ITERS 8) -> 8 waves/CU = 2 waves/SIMD (R7 had 1): the second
// wave per SIMD covers residual DMA latency/issue stalls.
// vmcnt: 8 DMAs/tile/wave; only stage(it+1) outstanding -> vmcnt(8)
// guarantees tile it landed; final iter drains 0. DEPTH-2 WAR safe by
// program order (buffer reads are lgkm-consumed before the next stage to
// that buffer is issued; all staging wave-private).
// Predicted: vqa_main 35-40 -> 22-28 us, bench 227 -> ~195-200; if flat,
// the ~205 plateau is the harness floor -> ROOFLINE next round.
// ---------------------------------------------------------------------------

#define N_QUBITS 7
#define DIM 128
#define N_LAYERS 4
#define BATCH 262144
#define GRID 1024
#define ROWS 32                          // rows per X tile (16 per wave)
#define ITERS (BATCH / (GRID * ROWS))    // 8
#define DEPTH 2                          // X tile buffers in LDS (32 KB)

typedef short short8 __attribute__((ext_vector_type(8)));
typedef float f32x4 __attribute__((ext_vector_type(4)));
typedef unsigned int u32;
typedef __attribute__((address_space(1))) const u32 g_u32;
typedef __attribute__((address_space(3))) u32 l_u32;

__device__ __forceinline__ unsigned short f2bf(float f) {
  unsigned u = __builtin_bit_cast(unsigned, f);
  u += 0x7fffu + ((u >> 16) & 1u);   // RNE
  return (unsigned short)(u >> 16);
}

// [bf16(x) | bf16(y)<<16]: round-half-up add + v_perm byte select
__device__ __forceinline__ unsigned pk2(float x, float y) {
  unsigned ux = __builtin_bit_cast(unsigned, x) + 0x8000u;
  unsigned uy = __builtin_bit_cast(unsigned, y) + 0x8000u;
  return __builtin_amdgcn_perm(uy, ux, 0x07060302u);
}

__device__ __forceinline__ short8 pack_bf16(float4 lo, float4 hi) {
  uint4 d;
  d.x = pk2(lo.x, lo.y);
  d.y = pk2(lo.z, lo.w);
  d.z = pk2(hi.x, hi.y);
  d.w = pk2(hi.z, hi.w);
  return __builtin_bit_cast(short8, d);
}

// ---------------------------------------------------------------------------
// Kernel 1: one block (64 threads) per column c. State (128 complex) in LDS.
// Qubit w <-> bit (6-w) of the flattened index.  (unchanged, verified)
// ---------------------------------------------------------------------------
__global__ void sim_columns(const float* __restrict__ W,
                            float* __restrict__ Ur, float* __restrict__ Ui) {
  __shared__ float sr[DIM], si[DIM];
  const int c = blockIdx.x;
  const int t = threadIdx.x;  // 0..63

  sr[t] = (t == c) ? 1.f : 0.f;        si[t] = 0.f;
  sr[t + 64] = (t + 64 == c) ? 1.f : 0.f;  si[t + 64] = 0.f;
  __syncthreads();

  for (int l = 0; l < N_LAYERS; ++l) {
    for (int w = 0; w < N_QUBITS; ++w) {
      const float phi = W[(l * 7 + w) * 3 + 0];
      const float th  = W[(l * 7 + w) * 3 + 1];
      const float om  = W[(l * 7 + w) * 3 + 2];
      const float ch = __cosf(0.5f * th), sh = __sinf(0.5f * th);
      const float ap = 0.5f * (phi + om), am = 0.5f * (phi - om);
      const float cap = __cosf(ap), sap = __sinf(ap);
      const float cam = __cosf(am), sam = __sinf(am);
      const float ar =  cap * ch, ai = -sap * ch;
      const float br = -cam * sh, bi = -sam * sh;
      const float cr =  cam * sh, ci = -sam * sh;
      const float dr =  cap * ch, di =  sap * ch;

      const int m = 1 << (6 - w);
      const int i0 = ((t & ~(m - 1)) << 1) | (t & (m - 1));
      const int i1 = i0 | m;
      const float x0r = sr[i0], x0i = si[i0];
      const float x1r = sr[i1], x1i = si[i1];
      __syncthreads();
      sr[i0] = ar * x0r - ai * x0i + br * x1r - bi * x1i;
      si[i0] = ar * x0i + ai * x0r + br * x1i + bi * x1r;
      sr[i1] = cr * x0r - ci * x0i + dr * x1r - di * x1i;
      si[i1] = cr * x0i + ci * x0r + dr * x1i + di * x1r;
      __syncthreads();
    }
    const int r = (l % (N_QUBITS - 1)) + 1;  // ranges [1,2,3,4]
    for (int w = 0; w < N_QUBITS; ++w) {
      const int ctrl = w, tgt = (w + r) % N_QUBITS;
      const int cmask = 1 << (6 - ctrl), tmask = 1 << (6 - tgt);
      const int i0 = ((t & ~(tmask - 1)) << 1) | (t & (tmask - 1));
      const int i1 = i0 | tmask;
      const float a0r = sr[i0], a0i = si[i0];
      const float a1r = sr[i1], a1i = si[i1];
      __syncthreads();
      if (i0 & cmask) {
        sr[i0] = a1r; si[i0] = a1i;
        sr[i1] = a0r; si[i1] = a0i;
      }
      __syncthreads();
    }
  }
  Ur[(size_t)t * DIM + c]        = sr[t];
  Ui[(size_t)t * DIM + c]        = si[t];
  Ur[(size_t)(t + 64) * DIM + c] = sr[t + 64];
  Ui[(size_t)(t + 64) * DIM + c] = si[t + 64];
}

// ---------------------------------------------------------------------------
// Kernel 2: A_ij, identity k-layout. 128 blocks (row i) x 128 threads (j).
// Ur[k][i] broadcasts; Ur[k][j] coalesces; all L2-hot.  (unchanged, verified)
// ---------------------------------------------------------------------------
__global__ void build_A(const float* __restrict__ Ur, const float* __restrict__ Ui,
                        unsigned short* __restrict__ Ab) {
  const int i = blockIdx.x;
  const int j = threadIdx.x;
  float s = 0.f;
#pragma unroll 8
  for (int k = 0; k < DIM; ++k) {
    const float zk = (((k >> 6) ^ k) & 1) ? -1.f : 1.f;
    s += zk * (Ur[k * DIM + i] * Ur[k * DIM + j] + Ui[k * DIM + i] * Ui[k * DIM + j]);
  }
  Ab[i * DIM + j] = f2bf(s);
}

// ---------------------------------------------------------------------------
// Per-WAVE stage of one tile's half (the wave's own 16 rows = 8 KB = 8 DMAs).
// LDS slot s holds global chunk (row = s>>5, c = (s&31) ^ (row&7)) -- source-
// side swizzle because the DMA's LDS dest is wave-uniform base + lane*16
// (m104) and can't scatter.
// ---------------------------------------------------------------------------
__device__ __forceinline__ void stage_half(const float* __restrict__ X, float* XsBuf,
                                           int tile, int wave, int lane) {
#pragma unroll
  for (int j = 0; j < 8; ++j) {
    const int s = 512 * wave + 64 * j + lane;   // slot id within this buffer
    const int row = s >> 5;
    const int c = (s & 31) ^ (row & 7);         // swizzled source chunk
    const float* gp = X + (size_t)tile * (ROWS * DIM) + row * DIM + c * 4;
    __builtin_amdgcn_global_load_lds((g_u32*)gp, (l_u32*)(XsBuf + s * 4), 16, 0, 0);
  }
}

// ---------------------------------------------------------------------------
// Kernel 3. Block = 2 waves; wave w owns tile rows 16w..16w+15. No barriers.
//   A-frag: a_frag[kt][t] = Ab[16t + n16][32kt + 8g .. +8]   (128 VGPRs)
//   B-frag: row R = 16w + n16, chunks (8kt+2g)^rx, (8kt+2g+1)^rx (2x b128)
//   C/D:    acc[t][r] = y[16t + 4g + r][n16]; epilogue xe chunk (4t+g)^rx.
// Quarter-wave read phases (fixed g, R over 16 rows): (c0 ^ (R&7)) covers
// every 4-bank group exactly twice = 2-way = free (m136).
// DEPTH=2 alternating buffers; counted s_waitcnt vmcnt(8) (tail 0) per wave.
// WAR on buffer reuse is safe: buffer b's ds_reads are lgkm-consumed before
// the next stage into b is issued (program order, wave-private rows).
// ---------------------------------------------------------------------------
__global__ __launch_bounds__(128, 2) void vqa_main(const float* __restrict__ X,
                                                   const unsigned short* __restrict__ Ab,
                                                   float* __restrict__ out) {
  __shared__ float Xs[DEPTH * ROWS * DIM];   // 2 x 16 KB = 32 KB

  const int tid = threadIdx.x;   // 0..127
  const int lane = tid & 63;
  const int wave = tid >> 6;     // 0..1
  const int n16 = lane & 15;
  const int g = lane >> 4;
  const int R = 16 * wave + n16; // this lane's row within the tile (0..31)
  const int rx = R & 7;          // row swizzle key

  // loop-invariant A fragments -> registers (32 x 16 B = 128 VGPRs); L2-hot
  short8 a_frag[4][8];
#pragma unroll
  for (int kt = 0; kt < 4; ++kt)
#pragma unroll
    for (int t = 0; t < 8; ++t)
      a_frag[kt][t] = *reinterpret_cast<const short8*>(
          Ab + (16 * t + n16) * DIM + 32 * kt + 8 * g);

  // prologue: stage tile 0
  stage_half(X, Xs, blockIdx.x, wave, lane);

#pragma unroll 1
  for (int it = 0; it < ITERS; ++it) {
    const int cur = it & 1;

    // issue next tile's DMA into the other buffer, then counted wait:
    // 8 newest outstanding = stage(it+1); everything older (tile it's DMAs,
    // prior out-stores) forced complete.
    if (it + 1 < ITERS) {
      stage_half(X, Xs + (cur ^ 1) * (ROWS * DIM),
                 blockIdx.x + (it + 1) * GRID, wave, lane);
      asm volatile("s_waitcnt vmcnt(8)" ::: "memory");
    } else {
      asm volatile("s_waitcnt vmcnt(0)" ::: "memory");
    }

    const int rb = cur * (ROWS * 32) + R * 32;   // row's first slot in cur buf

    // B-fragments from LDS
    short8 bfrag[4];
#pragma unroll
    for (int kt = 0; kt < 4; ++kt) {
      const int c0 = 8 * kt + 2 * g;
      const float4 lo = *reinterpret_cast<const float4*>(Xs + (rb + (c0 ^ rx)) * 4);
      const float4 hi = *reinterpret_cast<const float4*>(Xs + (rb + ((c0 + 1) ^ rx)) * 4);
      bfrag[kt] = pack_bf16(lo, hi);
    }

    f32x4 acc[8];
#pragma unroll
    for (int t = 0; t < 8; ++t) acc[t] = (f32x4){0.f, 0.f, 0.f, 0.f};
#pragma unroll
    for (int kt = 0; kt < 4; ++kt) {
#pragma unroll
      for (int t = 0; t < 8; ++t)
        acc[t] = __builtin_amdgcn_mfma_f32_16x16x32_bf16(a_frag[kt][t], bfrag[kt],
                                                         acc[t], 0, 0, 0);
    }

    // epilogue: x re-read from the (still intact) cur buffer after MFMAs
    float dot = 0.f, nrm = 0.f;
#pragma unroll
    for (int t = 0; t < 8; ++t) {
      const float4 xe = *reinterpret_cast<const float4*>(Xs + (rb + ((4 * t + g) ^ rx)) * 4);
      dot += xe.x * acc[t][0] + xe.y * acc[t][1] + xe.z * acc[t][2] + xe.w * acc[t][3];
      nrm += xe.x * xe.x + xe.y * xe.y + xe.z * xe.z + xe.w * xe.w;
    }
    dot += __shfl_xor(dot, 16, 64);
    dot += __shfl_xor(dot, 32, 64);
    nrm += __shfl_xor(nrm, 16, 64);
    nrm += __shfl_xor(nrm, 32, 64);
    if (g == 0) out[(blockIdx.x + it * GRID) * ROWS + R] = dot / nrm;
  }
}

// ---------------------------------------------------------------------------
extern "C" void kernel_launch(void* const* d_in, const int* in_sizes, int n_in,
                              void* d_out, int out_size, void* d_ws, size_t ws_size,
                              hipStream_t stream) {
  const float* X = (const float*)d_in[0];   // (262144, 128) fp32
  const float* W = (const float*)d_in[1];   // (4, 7, 3) fp32
  float* out = (float*)d_out;               // (262144,) fp32

  float* Ur = (float*)d_ws;
  float* Ui = Ur + DIM * DIM;
  unsigned short* Ab = (unsigned short*)(Ui + DIM * DIM);

  sim_columns<<<DIM, 64, 0, stream>>>(W, Ur, Ui);
  build_A<<<DIM, DIM, 0, stream>>>(Ur, Ui, Ab);
  vqa_main<<<GRID, 128, 0, stream>>>(X, Ab, out);
}

// Round 7
// 204.324 us; speedup vs baseline: 1.1137x; 1.0377x over previous
//
#include <hip/hip_runtime.h>

// ---------------------------------------------------------------------------
// out[n] = x_n^T A x_n / (x_n^T x_n),  A = Re(U^H Z U), U = full circuit unitary
// Kernel 1: simulate circuit on 128 basis columns -> U (complex fp32) in ws
// Kernel 2: A_ij = sum_k z_k (Ur_ki Ur_kj + Ui_ki Ui_kj) -> bf16 A in ws
// Kernel 3: bf16 MFMA GEMM y = A x fused with dot/norm epilogue
//
// R12 -> R13: REVERT to the best-measured configuration (this exact source
// benched 205.3 us). Session evidence: six structural variants (counted
// vmcnt/DEPTH4 208.4, fused+grid-barrier 331, LDS-free 216/228, 2 wv/SIMD
// 212.0) bracket a 205-228 band; occupancy, pipeline depth, and staging
// path are all perf-neutral at the bench level because the measurable time
// is dominated by the harness's fixed reset work (512 MB ws poison = 77 us
// at 86% HBM peak + input restore, ~131-165 us total) plus ~75 us of kernel
// time that no structural change moved. This config is the measured min.
// Predicted: dur_us 205-210, absmax 0.001953125; if confirmed -> ROOFLINE.
// ---------------------------------------------------------------------------

#define N_QUBITS 7
#define DIM 128
#define N_LAYERS 4
#define BATCH 262144
#define GRID 512
#define ROWS 32                          // rows per X tile
#define ITERS (BATCH / (GRID * ROWS))    // 16

typedef short short8 __attribute__((ext_vector_type(8)));
typedef float f32x4 __attribute__((ext_vector_type(4)));
typedef unsigned int u32;
typedef __attribute__((address_space(1))) const u32 g_u32;
typedef __attribute__((address_space(3))) u32 l_u32;

__device__ __forceinline__ unsigned short f2bf(float f) {
  unsigned u = __builtin_bit_cast(unsigned, f);
  u += 0x7fffu + ((u >> 16) & 1u);   // RNE
  return (unsigned short)(u >> 16);
}

// [bf16(x) | bf16(y)<<16]: round-half-up add + v_perm byte select
__device__ __forceinline__ unsigned pk2(float x, float y) {
  unsigned ux = __builtin_bit_cast(unsigned, x) + 0x8000u;
  unsigned uy = __builtin_bit_cast(unsigned, y) + 0x8000u;
  return __builtin_amdgcn_perm(uy, ux, 0x07060302u);
}

__device__ __forceinline__ short8 pack_bf16(float4 lo, float4 hi) {
  uint4 d;
  d.x = pk2(lo.x, lo.y);
  d.y = pk2(lo.z, lo.w);
  d.z = pk2(hi.x, hi.y);
  d.w = pk2(hi.z, hi.w);
  return __builtin_bit_cast(short8, d);
}

// ---------------------------------------------------------------------------
// Kernel 1: one block (64 threads) per column c. State (128 complex) in LDS.
// Qubit w <-> bit (6-w) of the flattened index.
// ---------------------------------------------------------------------------
__global__ void sim_columns(const float* __restrict__ W,
                            float* __restrict__ Ur, float* __restrict__ Ui) {
  __shared__ float sr[DIM], si[DIM];
  const int c = blockIdx.x;
  const int t = threadIdx.x;  // 0..63

  sr[t] = (t == c) ? 1.f : 0.f;        si[t] = 0.f;
  sr[t + 64] = (t + 64 == c) ? 1.f : 0.f;  si[t + 64] = 0.f;
  __syncthreads();

  for (int l = 0; l < N_LAYERS; ++l) {
    for (int w = 0; w < N_QUBITS; ++w) {
      const float phi = W[(l * 7 + w) * 3 + 0];
      const float th  = W[(l * 7 + w) * 3 + 1];
      const float om  = W[(l * 7 + w) * 3 + 2];
      const float ch = __cosf(0.5f * th), sh = __sinf(0.5f * th);
      const float ap = 0.5f * (phi + om), am = 0.5f * (phi - om);
      const float cap = __cosf(ap), sap = __sinf(ap);
      const float cam = __cosf(am), sam = __sinf(am);
      const float ar =  cap * ch, ai = -sap * ch;
      const float br = -cam * sh, bi = -sam * sh;
      const float cr =  cam * sh, ci = -sam * sh;
      const float dr =  cap * ch, di =  sap * ch;

      const int m = 1 << (6 - w);
      const int i0 = ((t & ~(m - 1)) << 1) | (t & (m - 1));
      const int i1 = i0 | m;
      const float x0r = sr[i0], x0i = si[i0];
      const float x1r = sr[i1], x1i = si[i1];
      __syncthreads();
      sr[i0] = ar * x0r - ai * x0i + br * x1r - bi * x1i;
      si[i0] = ar * x0i + ai * x0r + br * x1i + bi * x1r;
      sr[i1] = cr * x0r - ci * x0i + dr * x1r - di * x1i;
      si[i1] = cr * x0i + ci * x0r + dr * x1i + di * x1r;
      __syncthreads();
    }
    const int r = (l % (N_QUBITS - 1)) + 1;  // ranges [1,2,3,4]
    for (int w = 0; w < N_QUBITS; ++w) {
      const int ctrl = w, tgt = (w + r) % N_QUBITS;
      const int cmask = 1 << (6 - ctrl), tmask = 1 << (6 - tgt);
      const int i0 = ((t & ~(tmask - 1)) << 1) | (t & (tmask - 1));
      const int i1 = i0 | tmask;
      const float a0r = sr[i0], a0i = si[i0];
      const float a1r = sr[i1], a1i = si[i1];
      __syncthreads();
      if (i0 & cmask) {
        sr[i0] = a1r; si[i0] = a1i;
        sr[i1] = a0r; si[i1] = a0i;
      }
      __syncthreads();
    }
  }
  Ur[(size_t)t * DIM + c]        = sr[t];
  Ui[(size_t)t * DIM + c]        = si[t];
  Ur[(size_t)(t + 64) * DIM + c] = sr[t + 64];
  Ui[(size_t)(t + 64) * DIM + c] = si[t + 64];
}

// ---------------------------------------------------------------------------
// Kernel 2: A_ij, identity k-layout. 128 blocks (row i) x 128 threads (j).
// Ur[k][i] broadcasts; Ur[k][j] coalesces; all L2-hot.
// ---------------------------------------------------------------------------
__global__ void build_A(const float* __restrict__ Ur, const float* __restrict__ Ui,
                        unsigned short* __restrict__ Ab) {
  const int i = blockIdx.x;
  const int j = threadIdx.x;
  float s = 0.f;
#pragma unroll 8
  for (int k = 0; k < DIM; ++k) {
    const float zk = (((k >> 6) ^ k) & 1) ? -1.f : 1.f;
    s += zk * (Ur[k * DIM + i] * Ur[k * DIM + j] + Ui[k * DIM + i] * Ui[k * DIM + j]);
  }
  Ab[i * DIM + j] = f2bf(s);
}

// ---------------------------------------------------------------------------
// DMA one 32-row X tile (16 KB) into the given Xs buffer. LDS slot
// s = tid + 128j holds global chunk (row = s>>5, c = (s&31) ^ (row&7)) --
// source-side swizzle because the DMA's LDS dest is wave-uniform base +
// lane*16 (m104) and can't scatter. Per wave the 64 lane dests are
// contiguous 16B slots in lane order, as the hardware requires.
// ---------------------------------------------------------------------------
__device__ __forceinline__ void stage_tile(const float* __restrict__ X, float* XsBuf,
                                           int tile, int tid) {
#pragma unroll
  for (int j = 0; j < 8; ++j) {
    const int s = tid + 128 * j;              // LDS 16B-slot id, 0..1023
    const int row = s >> 5;
    const int c = (s & 31) ^ (row & 7);       // swizzled source chunk
    const float* gp = X + (size_t)tile * (ROWS * DIM) + row * DIM + c * 4;
    __builtin_amdgcn_global_load_lds((g_u32*)gp, (l_u32*)(XsBuf + s * 4), 16, 0, 0);
  }
}

// ---------------------------------------------------------------------------
// Kernel 3. Block = 2 waves; wave w owns tile rows 16w..16w+15.
//   A-frag: lane holds Ab[m = 16t + n16][k = 32kt + 8g + j]   (LDS, swizzled)
//   B-frag: row R = 16w + n16, chunks (8kt+2g)^rx, (8kt+2g+1)^rx (2x b128)
//   C/D:    acc[t][r] = y[16t + 4g + r][n16]; epilogue xe chunk (4t+g)^rx,
//           read AFTER the MFMAs (cur buffer stays intact -- dbuf).
// Quarter-wave read phases (fixed g, R over 16 rows): (c0 ^ (R&7)) covers
// every 4-bank group exactly twice = 2-way = free (m136).
// One barrier per iteration; its vmcnt drain targets the DMA issued in the
// PREVIOUS iteration body (prefetch distance ~ a full iteration of compute).
// ---------------------------------------------------------------------------
__global__ __launch_bounds__(128, 2) void vqa_main(const float* __restrict__ X,
                                                   const unsigned short* __restrict__ Ab,
                                                   float* __restrict__ out) {
  __shared__ unsigned short As[DIM * DIM];   // 32 KB
  __shared__ float Xs[2 * ROWS * DIM];       // 2 x 16 KB

  const int tid = threadIdx.x;   // 0..127
  const int lane = tid & 63;
  const int wave = tid >> 6;     // 0..1
  const int n16 = lane & 15;
  const int g = lane >> 4;

  // start DMA of tile 0 into buf 0; flies under the A-fill
  stage_tile(X, Xs, blockIdx.x, tid);

  // fill A into LDS with chunk swizzle (source L2-hot); 16 chunks/thread
#pragma unroll
  for (int i = 0; i < 16; ++i) {
    const int q = tid + 128 * i;          // 16B-chunk id, 0..2047
    const int m = q >> 4, c = q & 15;
    const short8 v = *reinterpret_cast<const short8*>(Ab + q * 8);
    *reinterpret_cast<short8*>(As + m * DIM + ((c ^ (m & 15)) << 3)) = v;
  }

  const unsigned short* abase[4];
#pragma unroll
  for (int kt = 0; kt < 4; ++kt)
    abase[kt] = As + n16 * DIM + (((4 * kt + g) ^ n16) << 3);

  const int R = 16 * wave + n16;   // this lane's row within the tile (0..31)
  const int rx = R & 7;            // row swizzle key

#pragma unroll 1
  for (int it = 0; it < ITERS; ++it) {
    const int cur = it & 1;
    const int rb = cur * (ROWS * 32) + R * 32;   // row's first slot in cur buf

    // drain: DMA(cur) issued last iteration (+ A-fill on it==0), then barrier
    asm volatile("s_waitcnt vmcnt(0)" ::: "memory");
    __syncthreads();

    // B-fragments from LDS
    short8 bfrag[4];
#pragma unroll
    for (int kt = 0; kt < 4; ++kt) {
      const int c0 = 8 * kt + 2 * g;
      const float4 lo = *reinterpret_cast<const float4*>(Xs + (rb + (c0 ^ rx)) * 4);
      const float4 hi = *reinterpret_cast<const float4*>(Xs + (rb + ((c0 + 1) ^ rx)) * 4);
      bfrag[kt] = pack_bf16(lo, hi);
    }

    // issue next tile's DMA into the OTHER buffer (no aliasing possible)
    if (it + 1 < ITERS)
      stage_tile(X, Xs + (cur ^ 1) * (ROWS * DIM), blockIdx.x + (it + 1) * GRID, tid);

    f32x4 acc[8];
#pragma unroll
    for (int t = 0; t < 8; ++t) acc[t] = (f32x4){0.f, 0.f, 0.f, 0.f};
#pragma unroll
    for (int kt = 0; kt < 4; ++kt) {
#pragma unroll
      for (int t = 0; t < 8; ++t) {
        const short8 af = *reinterpret_cast<const short8*>(abase[kt] + t * 16 * DIM);
        acc[t] = __builtin_amdgcn_mfma_f32_16x16x32_bf16(af, bfrag[kt], acc[t], 0, 0, 0);
      }
    }

    // epilogue: x re-read from the (still intact) cur buffer after MFMAs
    float dot = 0.f, nrm = 0.f;
#pragma unroll
    for (int t = 0; t < 8; ++t) {
      const float4 xe = *reinterpret_cast<const float4*>(Xs + (rb + ((4 * t + g) ^ rx)) * 4);
      dot += xe.x * acc[t][0] + xe.y * acc[t][1] + xe.z * acc[t][2] + xe.w * acc[t][3];
      nrm += xe.x * xe.x + xe.y * xe.y + xe.z * xe.z + xe.w * xe.w;
    }
    dot += __shfl_xor(dot, 16, 64);
    dot += __shfl_xor(dot, 32, 64);
    nrm += __shfl_xor(nrm, 16, 64);
    nrm += __shfl_xor(nrm, 32, 64);
    if (lane < 16) out[(blockIdx.x + it * GRID) * ROWS + R] = dot / nrm;
  }
}

// ---------------------------------------------------------------------------
extern "C" void kernel_launch(void* const* d_in, const int* in_sizes, int n_in,
                              void* d_out, int out_size, void* d_ws, size_t ws_size,
                              hipStream_t stream) {
  const float* X = (const float*)d_in[0];   // (262144, 128) fp32
  const float* W = (const float*)d_in[1];   // (4, 7, 3) fp32
  float* out = (float*)d_out;               // (262144,) fp32

  float* Ur = (float*)d_ws;
  float* Ui = Ur + DIM * DIM;
  unsigned short* Ab = (unsigned short*)(Ui + DIM * DIM);

  sim_columns<<<DIM, 64, 0, stream>>>(W, Ur, Ui);
  build_A<<<DIM, DIM, 0, stream>>>(Ur, Ui, Ab);
  vqa_main<<<GRID, 128, 0, stream>>>(X, Ab, out);
}